// Round 1
// baseline (208.740 us; speedup 1.0000x reference)
//
#include <hip/hip_runtime.h>

#define NUM_HEADS 8
#define DIM 64
#define NCLUST 512
#define NTOK 16384          // 8*2048 tokens
#define ROWLEN 512          // NUM_HEADS*DIM floats per token row
#define TB 64               // tokens per block in phase 1
#define KT 256              // clusters per LDS tile in phase 1
#define NIDS (NTOK * NUM_HEADS)          // 131072
#define NMEANS (NUM_HEADS * NCLUST * DIM) // 262144

// ---------------- kernel 0: q[h*K+k] = 0.5*|m_hk|^2 ----------------
__global__ void vq_qnorm(const float* __restrict__ means, float* __restrict__ q) {
    int i = blockIdx.x * blockDim.x + threadIdx.x;   // 0..4095
    const float4* m = (const float4*)(means + (size_t)i * DIM);
    float s = 0.f;
#pragma unroll
    for (int j = 0; j < DIM / 4; ++j) {
        float4 v = m[j];
        s += v.x * v.x + v.y * v.y + v.z * v.z + v.w * v.w;
    }
    q[i] = 0.5f * s;
}

// ---------------- kernel 1: scores + argmin ----------------
// Block: 256 threads, one head, TB=64 tokens, all 512 clusters (2 k-tiles of KT=256).
// Per-thread 8 tokens x 8 clusters register tile.
// score(k) = dot(x, m_k) - 0.5*|m_k|^2 ; argmax(score) == argmin(dist).
__global__ __launch_bounds__(256) void vq_argmin(const float* __restrict__ x,
                                                 const float* __restrict__ means,
                                                 const float* __restrict__ q,
                                                 float* __restrict__ out_ids) {
    __shared__ __align__(16) float xs[DIM][TB];   // 16 KB, xs[d][t]
    __shared__ __align__(16) float ms[DIM][KT];   // 64 KB, ms[d][k]

    const int head = blockIdx.y;
    const int t0 = blockIdx.x * TB;
    const int tid = threadIdx.x;

    // ---- stage x tile: token t = tid>>2 , 16-float chunk c = tid&3 ----
    {
        int t = tid >> 2, c = tid & 3;
        const float* src = x + (size_t)(t0 + t) * ROWLEN + head * DIM + c * 16;
#pragma unroll
        for (int j = 0; j < 4; ++j) {
            float4 v = *(const float4*)(src + j * 4);
            int d = c * 16 + j * 4;
            xs[d + 0][t] = v.x; xs[d + 1][t] = v.y;
            xs[d + 2][t] = v.z; xs[d + 3][t] = v.w;
        }
    }

    const int tx = tid & 31;   // cluster group (32 groups x 8 clusters)
    const int ty = tid >> 5;   // token group   (8 groups x 8 tokens)

    float best[8];
    int bestk[8];
#pragma unroll
    for (int i = 0; i < 8; ++i) { best[i] = -3.0e38f; bestk[i] = 0; }

    for (int kt = 0; kt < NCLUST / KT; ++kt) {
        const int kbase = kt * KT;
        __syncthreads();   // protect ms (and xs on first iter) from prior readers
        // ---- stage means tile: thread tid handles cluster kbase+tid ----
        {
            const float* src = means + ((size_t)head * NCLUST + kbase + tid) * DIM;
#pragma unroll
            for (int j = 0; j < 16; ++j) {
                float4 v = *(const float4*)(src + j * 4);
                int d = j * 4;
                ms[d + 0][tid] = v.x; ms[d + 1][tid] = v.y;
                ms[d + 2][tid] = v.z; ms[d + 3][tid] = v.w;
            }
        }
        __syncthreads();

        float acc[8][8];
#pragma unroll
        for (int i = 0; i < 8; ++i)
#pragma unroll
            for (int j = 0; j < 8; ++j) acc[i][j] = 0.f;

#pragma unroll 2
        for (int d = 0; d < DIM; ++d) {
            float xr[8], mr[8];
            *(float4*)&xr[0] = *(const float4*)&xs[d][ty * 8];
            *(float4*)&xr[4] = *(const float4*)&xs[d][ty * 8 + 4];
            *(float4*)&mr[0] = *(const float4*)&ms[d][tx * 4];
            *(float4*)&mr[4] = *(const float4*)&ms[d][KT / 2 + tx * 4];
#pragma unroll
            for (int i = 0; i < 8; ++i)
#pragma unroll
                for (int j = 0; j < 8; ++j)
                    acc[i][j] = fmaf(xr[i], mr[j], acc[i][j]);
        }

        // ---- fold in -0.5|m|^2 and update running argmax ----
#pragma unroll
        for (int j = 0; j < 8; ++j) {
            int k = kbase + ((j < 4) ? (tx * 4 + j) : (KT / 2 + tx * 4 + (j - 4)));
            float qv = q[head * NCLUST + k];
#pragma unroll
            for (int i = 0; i < 8; ++i) {
                float s = acc[i][j] - qv;
                if (s > best[i] || (s == best[i] && k < bestk[i])) {
                    best[i] = s; bestk[i] = k;
                }
            }
        }
    }

    // ---- reduce across the 32 cluster-groups (a half-wave shares tokens) ----
#pragma unroll
    for (int i = 0; i < 8; ++i) {
#pragma unroll
        for (int off = 16; off >= 1; off >>= 1) {
            float ob = __shfl_xor(best[i], off, 64);
            int   ok = __shfl_xor(bestk[i], off, 64);
            if (ob > best[i] || (ob == best[i] && ok < bestk[i])) {
                best[i] = ob; bestk[i] = ok;
            }
        }
    }
    if (tx == 0) {
#pragma unroll
        for (int i = 0; i < 8; ++i) {
            out_ids[(size_t)(t0 + ty * 8 + i) * NUM_HEADS + head] = (float)bestk[i];
        }
    }
}

// ---------------- kernel 2: scatter-accumulate sums & counts ----------------
// One 64-lane wave per (token, head) pair; lane = dim.
__global__ void vq_scatter(const float* __restrict__ x,
                           const float* __restrict__ ids_f,
                           float* __restrict__ counts,
                           float* __restrict__ sums) {
    int gthread = blockIdx.x * blockDim.x + threadIdx.x;
    int w = gthread >> 6;          // pair index, 0..131071
    int lane = threadIdx.x & 63;
    int token = w >> 3;
    int h = w & 7;
    int id = (int)ids_f[w];        // broadcast load
    float xv = x[(size_t)token * ROWLEN + h * DIM + lane];
    atomicAdd(&sums[(((size_t)h * NCLUST + id) << 6) + lane], xv);
    if (lane == 0) atomicAdd(&counts[h * NCLUST + id], 1.0f);
}

// ---------------- kernel 3: EMA finalize ----------------
__global__ void vq_final(const float* __restrict__ means,
                         const float* __restrict__ counts,
                         const float* __restrict__ sums,
                         float* __restrict__ out_means) {
    int i = blockIdx.x * blockDim.x + threadIdx.x;   // 0..262143
    float c = counts[i >> 6];
    float nm = sums[i] / (1e-6f + c);
    out_means[i] = 0.999f * means[i] + 0.001f * nm;
}

extern "C" void kernel_launch(void* const* d_in, const int* in_sizes, int n_in,
                              void* d_out, int out_size, void* d_ws, size_t ws_size,
                              hipStream_t stream) {
    const float* x     = (const float*)d_in[0];   // [8,2048,512]
    const float* means = (const float*)d_in[1];   // [8,512,64]

    float* out       = (float*)d_out;
    float* ids_f     = out;            // 131072 floats (cluster ids as float)
    float* out_means = out + NIDS;     // 262144 floats

    float* q      = (float*)d_ws;      // 4096
    float* counts = q + NUM_HEADS * NCLUST;       // 4096
    float* sums   = counts + NUM_HEADS * NCLUST;  // 262144

    // zero counts + sums every launch (ws is not re-poisoned between replays)
    hipMemsetAsync(counts, 0, (size_t)(NUM_HEADS * NCLUST + NMEANS) * sizeof(float), stream);

    vq_qnorm<<<(NUM_HEADS * NCLUST) / 256, 256, 0, stream>>>(means, q);

    dim3 g1(NTOK / TB, NUM_HEADS);
    vq_argmin<<<g1, 256, 0, stream>>>(x, means, q, ids_f);

    vq_scatter<<<(NIDS * 64) / 256, 256, 0, stream>>>(x, ids_f, counts, sums);

    vq_final<<<NMEANS / 256, 256, 0, stream>>>(means, counts, sums, out_means);
}

// Round 2
// 185.090 us; speedup vs baseline: 1.1278x; 1.1278x over previous
//
#include <hip/hip_runtime.h>

#define NUM_HEADS 8
#define DIM 64
#define NCLUST 512
#define NTOK 16384          // 8*2048 tokens
#define ROWLEN 512          // NUM_HEADS*DIM floats per token row
#define TB 64               // tokens per block in phase 1
#define KT 256              // clusters per LDS k-tile in phase 1
#define DT 32               // dims per LDS d-tile in phase 1
#define NIDS (NTOK * NUM_HEADS)           // 131072
#define NMEANS (NUM_HEADS * NCLUST * DIM) // 262144
#define NCK (NUM_HEADS * NCLUST)          // 4096

// ---------------- kernel 0: q[h*K+k] = 0.5*|m_hk|^2 ----------------
__global__ void vq_qnorm(const float* __restrict__ means, float* __restrict__ q) {
    int i = blockIdx.x * blockDim.x + threadIdx.x;   // 0..4095
    const float4* m = (const float4*)(means + (size_t)i * DIM);
    float s = 0.f;
#pragma unroll
    for (int j = 0; j < DIM / 4; ++j) {
        float4 v = m[j];
        s += v.x * v.x + v.y * v.y + v.z * v.z + v.w * v.w;
    }
    q[i] = 0.5f * s;
}

// ---------------- kernel 1: scores + argmin ----------------
// Block: 256 threads, one head, TB=64 tokens, 512 clusters (2 k-tiles of 256),
// means d-tiled (DT=32) so LDS = 16KB (xs) + 32KB (ms) = 48KB -> 3 blocks/CU.
// Per-thread 8 tokens x 8 clusters register tile; acc persists across d-tiles.
// score(k) = dot(x, m_k) - 0.5*|m_k|^2 ; argmax(score) == argmin(dist).
__global__ __launch_bounds__(256) void vq_argmin(const float* __restrict__ x,
                                                 const float* __restrict__ means,
                                                 const float* __restrict__ q,
                                                 float* __restrict__ out_ids) {
    __shared__ __align__(16) float xs[DIM][TB];   // 16 KB, xs[d][t]
    __shared__ __align__(16) float ms[DT][KT];    // 32 KB, ms[d][k]

    const int head = blockIdx.y;
    const int t0 = blockIdx.x * TB;
    const int tid = threadIdx.x;

    // ---- stage x tile: token t = tid&63, 16-float chunk c = tid>>6 ----
    // writes: bank = t%32 -> 2 lanes/bank (free)
    {
        int t = tid & 63, c = tid >> 6;
        const float* src = x + (size_t)(t0 + t) * ROWLEN + head * DIM + c * 16;
#pragma unroll
        for (int j = 0; j < 4; ++j) {
            float4 v = *(const float4*)(src + j * 4);
            int d = c * 16 + j * 4;
            xs[d + 0][t] = v.x; xs[d + 1][t] = v.y;
            xs[d + 2][t] = v.z; xs[d + 3][t] = v.w;
        }
    }

    const int tx = tid & 31;   // cluster group (32 groups x 8 clusters)
    const int ty = tid >> 5;   // token group   (8 groups x 8 tokens)

    float best[8];
    int bestk[8];
#pragma unroll
    for (int i = 0; i < 8; ++i) { best[i] = -3.0e38f; bestk[i] = 0; }

    for (int kt = 0; kt < NCLUST / KT; ++kt) {
        const int kbase = kt * KT;

        float acc[8][8];
#pragma unroll
        for (int i = 0; i < 8; ++i)
#pragma unroll
            for (int j = 0; j < 8; ++j) acc[i][j] = 0.f;

        for (int dt = 0; dt < DIM / DT; ++dt) {
            const int dbase = dt * DT;
            __syncthreads();   // prior readers of ms done (also covers xs stage, 1st iter)
            // ---- stage means d-slice: thread tid = cluster kbase+tid, dims dbase..+31 ----
            {
                const float* src = means + ((size_t)head * NCLUST + kbase + tid) * DIM + dbase;
#pragma unroll
                for (int j = 0; j < DT / 4; ++j) {
                    float4 v = *(const float4*)(src + j * 4);
                    int d = j * 4;
                    ms[d + 0][tid] = v.x; ms[d + 1][tid] = v.y;
                    ms[d + 2][tid] = v.z; ms[d + 3][tid] = v.w;
                }
            }
            __syncthreads();

#pragma unroll 4
            for (int d = 0; d < DT; ++d) {
                float xr[8], mr[8];
                *(float4*)&xr[0] = *(const float4*)&xs[dbase + d][ty * 8];
                *(float4*)&xr[4] = *(const float4*)&xs[dbase + d][ty * 8 + 4];
                *(float4*)&mr[0] = *(const float4*)&ms[d][tx * 4];
                *(float4*)&mr[4] = *(const float4*)&ms[d][KT / 2 + tx * 4];
#pragma unroll
                for (int i = 0; i < 8; ++i)
#pragma unroll
                    for (int j = 0; j < 8; ++j)
                        acc[i][j] = fmaf(xr[i], mr[j], acc[i][j]);
            }
        }

        // ---- fold in -0.5|m|^2 and update running argmax ----
#pragma unroll
        for (int j = 0; j < 8; ++j) {
            int k = kbase + ((j < 4) ? (tx * 4 + j) : (KT / 2 + tx * 4 + (j - 4)));
            float qv = q[head * NCLUST + k];
#pragma unroll
            for (int i = 0; i < 8; ++i) {
                float s = acc[i][j] - qv;
                if (s > best[i] || (s == best[i] && k < bestk[i])) {
                    best[i] = s; bestk[i] = k;
                }
            }
        }
    }

    // ---- reduce across the 32 cluster-groups (half-wave shares tokens) ----
#pragma unroll
    for (int i = 0; i < 8; ++i) {
#pragma unroll
        for (int off = 16; off >= 1; off >>= 1) {
            float ob = __shfl_xor(best[i], off, 64);
            int   ok = __shfl_xor(bestk[i], off, 64);
            if (ob > best[i] || (ob == best[i] && ok < bestk[i])) {
                best[i] = ob; bestk[i] = ok;
            }
        }
    }
    if (tx == 0) {
#pragma unroll
        for (int i = 0; i < 8; ++i) {
            out_ids[(size_t)(t0 + ty * 8 + i) * NUM_HEADS + head] = (float)bestk[i];
        }
    }
}

// ---------------- kernel 2: scatter-accumulate sums & counts ----------------
// One 64-lane wave per (token, head); lane = dim. Replicated accumulators
// (rep = token & (nrep-1)) cut per-address atomic contention.
__global__ void vq_scatter(const float* __restrict__ x,
                           const float* __restrict__ ids_f,
                           float* __restrict__ counts,
                           float* __restrict__ sums,
                           int rep_mask) {
    int gthread = blockIdx.x * blockDim.x + threadIdx.x;
    int w = gthread >> 6;          // pair index, 0..131071
    int lane = threadIdx.x & 63;
    int token = w >> 3;
    int h = w & 7;
    int rep = token & rep_mask;
    int id = (int)ids_f[w];        // broadcast load
    float xv = x[(size_t)token * ROWLEN + h * DIM + lane];
    atomicAdd(&sums[(size_t)rep * NMEANS + (((size_t)h * NCLUST + id) << 6) + lane], xv);
    if (lane == 0) atomicAdd(&counts[rep * NCK + h * NCLUST + id], 1.0f);
}

// ---------------- kernel 3: EMA finalize (sums replicas) ----------------
__global__ void vq_final(const float* __restrict__ means,
                         const float* __restrict__ counts,
                         const float* __restrict__ sums,
                         float* __restrict__ out_means,
                         int nrep) {
    int i = blockIdx.x * blockDim.x + threadIdx.x;   // 0..262143
    int ck = i >> 6;
    float c = 0.f, s = 0.f;
    for (int r = 0; r < nrep; ++r) {
        c += counts[r * NCK + ck];
        s += sums[(size_t)r * NMEANS + i];
    }
    float nm = s / (1e-6f + c);
    out_means[i] = 0.999f * means[i] + 0.001f * nm;
}

extern "C" void kernel_launch(void* const* d_in, const int* in_sizes, int n_in,
                              void* d_out, int out_size, void* d_ws, size_t ws_size,
                              hipStream_t stream) {
    const float* x     = (const float*)d_in[0];   // [8,2048,512]
    const float* means = (const float*)d_in[1];   // [8,512,64]

    float* out       = (float*)d_out;
    float* ids_f     = out;            // 131072 floats (cluster ids as float)
    float* out_means = out + NIDS;     // 262144 floats

    // choose replication factor by available workspace
    size_t need4 = (size_t)(NCK + 4 * NCK + 4 * NMEANS) * sizeof(float);
    int nrep = (ws_size >= need4) ? 4 : 1;

    float* q      = (float*)d_ws;                 // 4096
    float* counts = q + NCK;                      // nrep*4096
    float* sums   = counts + (size_t)nrep * NCK;  // nrep*262144

    // zero counts + sums every launch (ws is not re-poisoned between replays)
    hipMemsetAsync(counts, 0, (size_t)nrep * (NCK + NMEANS) * sizeof(float), stream);

    vq_qnorm<<<NCK / 256, 256, 0, stream>>>(means, q);

    dim3 g1(NTOK / TB, NUM_HEADS);
    vq_argmin<<<g1, 256, 0, stream>>>(x, means, q, ids_f);

    vq_scatter<<<(NIDS * 64) / 256, 256, 0, stream>>>(x, ids_f, counts, sums, nrep - 1);

    vq_final<<<NMEANS / 256, 256, 0, stream>>>(means, counts, sums, out_means, nrep);
}